// Round 3
// baseline (622.597 us; speedup 1.0000x reference)
//
#include <hip/hip_runtime.h>

#define BB 4
#define SS 2048
#define DD 256
#define HH 8

typedef unsigned short u16;
typedef __attribute__((ext_vector_type(8))) short bf16x8;
typedef __attribute__((ext_vector_type(4))) float f32x4;

__device__ __forceinline__ f32x4 MFMA(bf16x8 a, bf16x8 b, f32x4 c) {
    return __builtin_amdgcn_mfma_f32_16x16x32_bf16(a, b, c, 0, 0, 0);
}

__device__ __forceinline__ u16 f2bf_rtn(float x) {
    unsigned u = __float_as_uint(x);
    u += 0x7FFFu + ((u >> 16) & 1u);
    return (u16)(u >> 16);
}
__device__ __forceinline__ float bf2f(u16 h) {
    return __uint_as_float(((unsigned)h) << 16);
}
__device__ __forceinline__ void split2(float x, u16 &hi, u16 &lo) {
    hi = f2bf_rtn(x);
    lo = f2bf_rtn(x - bf2f(hi));
}

// ---------------- weight prep: transpose + hi/lo split ----------------
__global__ void prep_w(const float* __restrict__ W, u16* __restrict__ Whi,
                       u16* __restrict__ Wlo) {
    int n = blockIdx.x;            // 0..2047
    int h = n >> 8, e = n & 255;
    int d = threadIdx.x;           // 0..255
    float x = W[((size_t)h * 256 + d) * 256 + e];
    u16 hi, lo; split2(x, hi, lo);
    Whi[(size_t)n * 256 + d] = hi;
    Wlo[(size_t)n * 256 + d] = lo;
}

__global__ void prep_wo(const float* __restrict__ W, u16* __restrict__ Whi,
                        u16* __restrict__ Wlo) {
    int n = blockIdx.x;            // 0..255
    for (int k = threadIdx.x; k < 2048; k += 256) {
        float x = W[(size_t)k * 256 + n];
        u16 hi, lo; split2(x, hi, lo);
        Whi[(size_t)n * 2048 + k] = hi;
        Wlo[(size_t)n * 2048 + k] = lo;
    }
}

// ---------------- split-bf16 GEMM: C = A * B^T(stored [N][K]) + bias ----------------
// MODE 0: bf16-hi output -> Q/K layout [b][h][s][d]
// MODE 1: bf16-hi output -> V^T layout [b][h][d][s]
// MODE 2: fp32 output    -> C[row*N + col]
template<int MODE, bool AFP32, int TERMS, int BN>
__global__ __launch_bounds__(512, 2) void gemm_split(
    const float* __restrict__ Af,
    const u16* __restrict__ Ahi, const u16* __restrict__ Alo,
    const u16* __restrict__ Bhi, const u16* __restrict__ Blo,
    const float* __restrict__ bias,
    u16* __restrict__ Ohi,
    float* __restrict__ Of,
    int M, int N, int K, float scale)
{
    constexpr int WN = (BN == 128) ? 4 : 2;        // waves along n
    constexpr int WM = 8 / WN;                     // waves along m
    constexpr int MSUB = (128 / WM) / 16;
    constexpr int NSUB = (BN / WN) / 16;

    __shared__ u16 lA_hi[128][40], lA_lo[128][40];
    __shared__ u16 lB_hi[128][40], lB_lo[128][40];

    const int tid = threadIdx.x;
    const int lane = tid & 63, wave = tid >> 6;
    const int wm = wave / WN, wn = wave % WN;
    const int m0 = blockIdx.y * 128, n0 = blockIdx.x * BN;

    f32x4 acc[MSUB][NSUB];
#pragma unroll
    for (int i = 0; i < MSUB; ++i)
#pragma unroll
        for (int j = 0; j < NSUB; ++j) acc[i][j] = {0.f, 0.f, 0.f, 0.f};

    const int srow = tid >> 2;
    const int schunk = (tid & 3) * 8;

    for (int k0 = 0; k0 < K; k0 += 32) {
        __syncthreads();
        if (AFP32) {
            const float* g = Af + (size_t)(m0 + srow) * K + k0 + schunk;
            f32x4 a0 = *(const f32x4*)g;
            f32x4 a1 = *(const f32x4*)(g + 4);
            bf16x8 hv;
#pragma unroll
            for (int j = 0; j < 4; ++j) hv[j] = (short)f2bf_rtn(a0[j]);
#pragma unroll
            for (int j = 0; j < 4; ++j) hv[4 + j] = (short)f2bf_rtn(a1[j]);
            *(bf16x8*)&lA_hi[srow][schunk] = hv;
        } else {
            size_t ga = (size_t)(m0 + srow) * K + k0 + schunk;
            *(bf16x8*)&lA_hi[srow][schunk] = *(const bf16x8*)(Ahi + ga);
            if (TERMS == 3)
                *(bf16x8*)&lA_lo[srow][schunk] = *(const bf16x8*)(Alo + ga);
        }
        if (BN == 128 || tid < BN * 4) {
            size_t gb = (size_t)(n0 + srow) * K + k0 + schunk;
            *(bf16x8*)&lB_hi[srow][schunk] = *(const bf16x8*)(Bhi + gb);
            if (TERMS >= 2)
                *(bf16x8*)&lB_lo[srow][schunk] = *(const bf16x8*)(Blo + gb);
        }
        __syncthreads();

        const int kf = (lane >> 4) * 8;
        const int rA = wm * (128 / WM), rB = wn * (BN / WN);
        bf16x8 bh[NSUB], bl[NSUB];
#pragma unroll
        for (int ns = 0; ns < NSUB; ++ns) {
            bh[ns] = *(bf16x8*)&lB_hi[rB + ns * 16 + (lane & 15)][kf];
            if (TERMS >= 2)
                bl[ns] = *(bf16x8*)&lB_lo[rB + ns * 16 + (lane & 15)][kf];
        }
#pragma unroll
        for (int ms = 0; ms < MSUB; ++ms) {
            bf16x8 ah = *(bf16x8*)&lA_hi[rA + ms * 16 + (lane & 15)][kf];
            bf16x8 al;
            if (TERMS == 3) al = *(bf16x8*)&lA_lo[rA + ms * 16 + (lane & 15)][kf];
#pragma unroll
            for (int ns = 0; ns < NSUB; ++ns) {
                acc[ms][ns] = MFMA(ah, bh[ns], acc[ms][ns]);
                if (TERMS == 3) acc[ms][ns] = MFMA(al, bh[ns], acc[ms][ns]);
                if (TERMS >= 2) acc[ms][ns] = MFMA(ah, bl[ns], acc[ms][ns]);
            }
        }
    }

#pragma unroll
    for (int ms = 0; ms < MSUB; ++ms)
#pragma unroll
        for (int ns = 0; ns < NSUB; ++ns)
#pragma unroll
            for (int r = 0; r < 4; ++r) {
                int row = m0 + wm * (128 / WM) + ms * 16 + (lane >> 4) * 4 + r;
                int col = n0 + wn * (BN / WN) + ns * 16 + (lane & 15);
                float v = (acc[ms][ns][r] + bias[col]) * scale;
                if (MODE == 2) {
                    Of[(size_t)row * N + col] = v;
                } else {
                    int b = row >> 11, s = row & 2047, hh = col >> 8, e = col & 255;
                    size_t idx;
                    if (MODE == 0)
                        idx = ((size_t)(b * HH + hh) * SS + s) * DD + e;
                    else
                        idx = ((size_t)(b * HH + hh) * DD + e) * SS + s;
                    Ohi[idx] = f2bf_rtn(v);
                }
            }
}

// ---------------- flash attention: swapped QK^T, in-register P ----------------
// Q pre-scaled by log2(e)/16 -> logits in log2 domain.
// S^T = MFMA(K_frag, Q_frag): col=q=lane&15, row=logical k-row 4*(lane>>4)+r.
// K-frag rows use permutation pi_t(l) = 8*(l>>2)+(l&3)+4*(t&1)+32*(t>>1) so that
// the exp'd S^T registers ARE the PV B-operand fragments (keys linear per chunk).
__global__ __launch_bounds__(512, 2) void attn_kernel(
    const u16* __restrict__ Qhi,
    const u16* __restrict__ Khi,
    const u16* __restrict__ Vhi,
    u16* __restrict__ Rhi, u16* __restrict__ Rlo)
{
    __shared__ u16 lKh[64][264];     // K tile [key][d], d-cols XOR-swizzled by row
    __shared__ u16 lVh[256][72];     // V^T tile [e][key], pad 8

    const int tid = threadIdx.x, lane = tid & 63, wave = tid >> 6;
    const int m = lane & 15, g = lane >> 4;
    const int bh = blockIdx.y;                     // 0..31 (b*8+h)
    const size_t base = (size_t)bh * SS * DD;
    const int q0 = blockIdx.x * 128 + wave * 16;

    // Q fragments (B-operand: col=q=m, d-chunk = g*8 within ks*32)
    bf16x8 qh[8];
#pragma unroll
    for (int ks = 0; ks < 8; ++ks)
        qh[ks] = *(const bf16x8*)(Qhi + base + (size_t)(q0 + m) * DD + ks * 32 + g * 8);

    const int r0 = ((m >> 2) << 3) + (m & 3);      // pi base row
    const int swz = (m >> 2) << 5;                 // column XOR (u16 units)
    int kofs[8];                                   // byte offset into a K row
#pragma unroll
    for (int ks = 0; ks < 8; ++ks)
        kofs[ks] = ((((ks << 5) ^ swz) | (g << 3)) << 1);

    float m2 = -1e30f, l = 0.f;
    f32x4 acc[16];
#pragma unroll
    for (int e = 0; e < 16; ++e) acc[e] = {0.f, 0.f, 0.f, 0.f};

    for (int kv = 0; kv < SS; kv += 64) {
        __syncthreads();
        // stage K tile: 64 rows x 256 u16, swizzled columns
#pragma unroll
        for (int i = 0; i < 4; ++i) {
            int id = tid + i * 512;
            int r = id >> 5, c = (id & 31) << 3;
            *(bf16x8*)&lKh[r][c ^ (((r >> 3) & 3) << 5)] =
                *(const bf16x8*)(Khi + base + (size_t)(kv + r) * DD + c);
        }
        // stage V^T tile: 256 rows x 64 u16
#pragma unroll
        for (int i = 0; i < 4; ++i) {
            int id = tid + i * 512;
            int r = id >> 3, c = (id & 7) << 3;
            *(bf16x8*)&lVh[r][c] =
                *(const bf16x8*)(Vhi + base + (size_t)r * SS + kv + c);
        }
        __syncthreads();

        // QK^T (swapped): s[t] holds keys pi_t(4g+r) for q=m
        f32x4 s[4];
#pragma unroll
        for (int t = 0; t < 4; ++t) s[t] = {0.f, 0.f, 0.f, 0.f};
        const char* krow[4];
        krow[0] = (const char*)&lKh[r0][0];
        krow[1] = (const char*)&lKh[r0 + 4][0];
        krow[2] = (const char*)&lKh[r0 + 32][0];
        krow[3] = (const char*)&lKh[r0 + 36][0];
#pragma unroll
        for (int ks = 0; ks < 8; ++ks)
#pragma unroll
            for (int t = 0; t < 4; ++t) {
                bf16x8 kf_ = *(const bf16x8*)(krow[t] + kofs[ks]);
                s[t] = MFMA(kf_, qh[ks], s[t]);
            }

        // online softmax in log2 domain (all 16 in-lane values share q=m)
        f32x4 vm;
#pragma unroll
        for (int r = 0; r < 4; ++r)
            vm[r] = fmaxf(fmaxf(s[0][r], s[1][r]), fmaxf(s[2][r], s[3][r]));
        float mx = fmaxf(fmaxf(vm[0], vm[1]), fmaxf(vm[2], vm[3]));
        mx = fmaxf(mx, __shfl_xor(mx, 16));
        mx = fmaxf(mx, __shfl_xor(mx, 32));

        if (__ballot(mx > m2 + 11.0f)) {           // defer-rescale (T13)
            float mn = fmaxf(m2, mx);
            float f = __builtin_amdgcn_exp2f(m2 - mn);
            m2 = mn;
            l *= f;
#pragma unroll
            for (int e = 0; e < 16; ++e) acc[e] *= f;
        }
#pragma unroll
        for (int t = 0; t < 4; ++t)
#pragma unroll
            for (int r = 0; r < 4; ++r)
                s[t][r] = __builtin_amdgcn_exp2f(s[t][r] - m2);

        f32x4 vs = (s[0] + s[1]) + (s[2] + s[3]);
        float sum = (vs[0] + vs[1]) + (vs[2] + vs[3]);
        sum += __shfl_xor(sum, 16);
        sum += __shfl_xor(sum, 32);
        l += sum;

        // PV: O^T[e][q] += V^T[e][k] * P^T[k][q]; P frags are in-register
        const char* vbase = (const char*)&lVh[m][g << 3];
#pragma unroll
        for (int c = 0; c < 2; ++c) {
            bf16x8 pb;
#pragma unroll
            for (int j = 0; j < 4; ++j) pb[j] = (short)f2bf_rtn(s[2 * c][j]);
#pragma unroll
            for (int j = 0; j < 4; ++j) pb[4 + j] = (short)f2bf_rtn(s[2 * c + 1][j]);
#pragma unroll
            for (int e = 0; e < 16; ++e) {
                bf16x8 vf = *(const bf16x8*)(vbase + e * 2304 + c * 64);
                acc[e] = MFMA(vf, pb, acc[e]);
            }
        }
    }

    // epilogue: lane owns q=m; e = esub*16 + 4g + r
    const int b = bh >> 3, h = bh & 7;
    float inv = 1.0f / l;
    const size_t rowbase = ((size_t)(b * SS + q0 + m)) * (DD * HH) + h;
#pragma unroll
    for (int e16 = 0; e16 < 16; ++e16)
#pragma unroll
        for (int r = 0; r < 4; ++r) {
            int e = e16 * 16 + g * 4 + r;
            float v = acc[e16][r] * inv;
            u16 hh2, ll2; split2(v, hh2, ll2);
            Rhi[rowbase + (size_t)e * HH] = hh2;
            Rlo[rowbase + (size_t)e * HH] = ll2;
        }
}

// ---------------- launcher ----------------
extern "C" void kernel_launch(void* const* d_in, const int* in_sizes, int n_in,
                              void* d_out, int out_size, void* d_ws, size_t ws_size,
                              hipStream_t stream)
{
    (void)in_sizes; (void)n_in; (void)out_size; (void)ws_size;
    const float* k_in = (const float*)d_in[0];
    const float* v_in = (const float*)d_in[1];
    const float* q_in = (const float*)d_in[2];
    const float* Wk   = (const float*)d_in[3];
    const float* bk   = (const float*)d_in[4];
    const float* Wv   = (const float*)d_in[5];
    const float* bv   = (const float*)d_in[6];
    const float* Wq   = (const float*)d_in[7];
    const float* bq   = (const float*)d_in[8];
    const float* Wo   = (const float*)d_in[9];
    const float* bo   = (const float*)d_in[10];
    float* out = (float*)d_out;

    // workspace: 8 MB weights + 5 bf16 planes (32 MB each) = 168 MB total
    char* p = (char*)d_ws;
    const size_t MB = 1024 * 1024;
    u16* WqH = (u16*)(p + 0 * MB);
    u16* WqL = (u16*)(p + 1 * MB);
    u16* WkH = (u16*)(p + 2 * MB);
    u16* WkL = (u16*)(p + 3 * MB);
    u16* WvH = (u16*)(p + 4 * MB);
    u16* WvL = (u16*)(p + 5 * MB);
    u16* WoH = (u16*)(p + 6 * MB);
    u16* WoL = (u16*)(p + 7 * MB);
    const size_t PB = 32 * MB;
    u16* QH  = (u16*)(p + 8 * MB);
    u16* KH  = (u16*)(p + 8 * MB + 1 * PB);
    u16* VTH = (u16*)(p + 8 * MB + 2 * PB);
    u16* RH  = (u16*)(p + 8 * MB + 3 * PB);
    u16* RL  = (u16*)(p + 8 * MB + 4 * PB);

    prep_w<<<dim3(2048), dim3(256), 0, stream>>>(Wq, WqH, WqL);
    prep_w<<<dim3(2048), dim3(256), 0, stream>>>(Wk, WkH, WkL);
    prep_w<<<dim3(2048), dim3(256), 0, stream>>>(Wv, WvH, WvL);
    prep_wo<<<dim3(256), dim3(256), 0, stream>>>(Wo, WoH, WoL);

    // projections: M=8192, N=2048, K=256.
    // Q scaled by log2(e)/sqrt(D) = log2(e)/16 -> logits directly in log2 domain.
    const float qscale = 1.4426950408889634f / 16.0f;
    gemm_split<0, true, 1, 128><<<dim3(16, 64), dim3(512), 0, stream>>>(
        q_in, nullptr, nullptr, WqH, WqL, bq, QH, nullptr, 8192, 2048, 256, qscale);
    gemm_split<0, true, 1, 128><<<dim3(16, 64), dim3(512), 0, stream>>>(
        k_in, nullptr, nullptr, WkH, WkL, bk, KH, nullptr, 8192, 2048, 256, 1.0f);
    gemm_split<1, true, 2, 128><<<dim3(16, 64), dim3(512), 0, stream>>>(
        v_in, nullptr, nullptr, WvH, WvL, bv, VTH, nullptr, 8192, 2048, 256, 1.0f);

    // flash attention: 16 q-tiles x 32 (b,h)
    attn_kernel<<<dim3(16, 32), dim3(512), 0, stream>>>(
        QH, KH, VTH, RH, RL);

    // output projection: M=8192, N=256, K=2048; 128x64 tiles -> 256 blocks
    gemm_split<2, false, 3, 64><<<dim3(4, 64), dim3(512), 0, stream>>>(
        nullptr, RH, RL, WoH, WoL, bo, nullptr, out, 8192, 256, 2048, 1.0f);
}